// Round 8
// baseline (202.799 us; speedup 1.0000x reference)
//
#include <hip/hip_runtime.h>

// ---------------------------------------------------------------------------
// IntraModalityEnhance — fp32 in/out, bf16 MFMA internals.
// B=2, S=2048, D=1024, H=16, HD=64, E=1024, W=31 (+pos,+fsq keys = 33).
//
//  prep       : ONE launch — x/fsq/pos -> bf16  +  Wq/Wk/Wv/Wo transposes
//  proj_gemm  : ONE launch, 1152 blocks, XCD tm-slab swizzle; BK=64,
//               XOR-swizzled LDS, global_load_lds x16.  K -> Kp row-major,
//               V -> VpT[n][m] (transposed, 8B packed stores), Q -> Qp.
//               LDS buffers hoisted to kernel scope (ONE 32 KB allocation —
//               function-scope __shared__ duplicated per inlined template
//               instantiation cost 64 KB and halved occupancy in R7).
//  attn_tile  : block=(b,h,32 s); staging via global_load_lds DMA,
//               MFMA QK^T/PV; boundary blocks take register path.
//  out_gemm   : BM=64, 512 blocks, XCD tm-slab swizzle -> d_out fp32
// ---------------------------------------------------------------------------

typedef __attribute__((ext_vector_type(8))) short bf16x8;
typedef __attribute__((ext_vector_type(4))) float f32x4;
typedef unsigned short u16;
typedef unsigned int u32;
typedef unsigned long long u64;

__device__ __forceinline__ float bf2f(u16 u) {
  union { u32 i; float f; } v; v.i = ((u32)u) << 16; return v.f;
}
__device__ __forceinline__ u16 f2bf(float f) {
  union { float f; u32 i; } v; v.f = f;
  u32 r = v.i + 0x7fffu + ((v.i >> 16) & 1u);
  return (u16)(r >> 16);
}
__device__ __forceinline__ float2 unpk(u32 u) {
  union { u32 i; float f; } lo, hi;
  lo.i = u << 16; hi.i = u & 0xffff0000u;
  return make_float2(lo.f, hi.f);
}
__device__ __forceinline__ float dot8(uint4 a, uint4 b) {
  float s = 0.f;
  { float2 x = unpk(a.x), y = unpk(b.x); s += x.x*y.x + x.y*y.y; }
  { float2 x = unpk(a.y), y = unpk(b.y); s += x.x*y.x + x.y*y.y; }
  { float2 x = unpk(a.z), y = unpk(b.z); s += x.x*y.x + x.y*y.y; }
  { float2 x = unpk(a.w), y = unpk(b.w); s += x.x*y.x + x.y*y.y; }
  return s;
}
__device__ __forceinline__ void gload_lds16(const u16* g, u16* l) {
  __builtin_amdgcn_global_load_lds((const __attribute__((address_space(1))) void*)(g),
                                   (__attribute__((address_space(3))) void*)(l),
                                   16, 0, 0);
}
__device__ __forceinline__ uint4 pack8(float4 a, float4 b) {
  union { u16 h[8]; uint4 q; } u;
  u.h[0] = f2bf(a.x); u.h[1] = f2bf(a.y); u.h[2] = f2bf(a.z); u.h[3] = f2bf(a.w);
  u.h[4] = f2bf(b.x); u.h[5] = f2bf(b.y); u.h[6] = f2bf(b.z); u.h[7] = f2bf(b.w);
  return u.q;
}

// ---------------------------------------------------------------------------
__device__ __forceinline__ void transpose_body(const float* src, u16* dst,
                                               int R, int C, int r0, int c0) {
  __shared__ u16 tile[64][72];
  int t = threadIdx.x;
#pragma unroll
  for (int i = 0; i < 16; ++i) {
    int idx = i * 256 + t;
    int r = idx >> 6, c = idx & 63;
    tile[r][c] = f2bf(src[(size_t)(r0 + r) * C + (c0 + c)]);
  }
  __syncthreads();
#pragma unroll
  for (int i = 0; i < 16; ++i) {
    int idx = i * 256 + t;
    int c = idx >> 6, r = idx & 63;
    dst[(size_t)(c0 + c) * R + (r0 + r)] = tile[r][c];
  }
}

// ONE launch: blocks 0..4095 convert x/fsq/pos; 4096..5119 transpose weights.
__global__ __launch_bounds__(256) void prep(const float* __restrict__ x,
                                            const float* __restrict__ fsq,
                                            const float* __restrict__ pos,
                                            const float* __restrict__ Wq,
                                            const float* __restrict__ Wk,
                                            const float* __restrict__ Wv,
                                            const float* __restrict__ Wo,
                                            u16* __restrict__ xb,
                                            u16* __restrict__ fsqb,
                                            u16* __restrict__ posb,
                                            u16* __restrict__ WqT,
                                            u16* __restrict__ WkT,
                                            u16* __restrict__ WvT,
                                            u16* __restrict__ WoT) {
  int bid = blockIdx.x;
  if (bid < 4096) {
    int i = bid * 256 + threadIdx.x;
    const float* src; u16* dst; int off;
    if (i < 524288)      { src = x;   dst = xb;   off = i; }
    else if (i < 786432) { src = fsq; dst = fsqb; off = i - 524288; }
    else                 { src = pos; dst = posb; off = i - 786432; }
    float4 a = ((const float4*)src)[2 * off];
    float4 b = ((const float4*)src)[2 * off + 1];
    ((uint4*)dst)[off] = pack8(a, b);
  } else {
    int id = bid - 4096;
    int z = id >> 8, rest = id & 255;
    int xx = rest & 15, yy = rest >> 4;
    if (z < 3) {
      const float* s = (z == 0) ? Wq : (z == 1) ? Wk : Wv;
      u16* d = (z == 0) ? WqT : (z == 1) ? WkT : WvT;
      size_t off = (size_t)xx * 65536;    // head * 1024 * 64
      transpose_body(s + off, d + off, 1024, 64, yy * 64, 0);
    } else {
      transpose_body(Wo, WoT, 1024, 1024, yy * 64, xx * 64);
    }
  }
}

// ---------------------------------------------------------------------------
// GEMM body: BM = MT*32, BN=128, BK=64, XOR-swizzled LDS, global_load_lds x16.
// LDS buffers are caller-owned (As: MT*32*64 u16, Bs: 128*64 u16) so multiple
// inlined instantiations share ONE allocation.
// OMODE: 0 = bf16 row-major C[m][1024], 1 = fp32 row-major,
//        2 = bf16 TRANSPOSED CT[n][8192] (packed 4-elem 8B stores).
// ---------------------------------------------------------------------------
__device__ __forceinline__ int swz(int R, int c) {   // u16 index of 16B chunk
  return (R * 8 + (c ^ (R & 7))) * 8;
}

template <int MT, int OMODE>
__device__ __forceinline__ void gemm_body(u16* __restrict__ As,
                                          u16* __restrict__ Bs,
                                          const u16* __restrict__ Ap,
                                          const u16* __restrict__ BT,
                                          const float* __restrict__ bias,
                                          void* Cp, int tile_n, int tile_m) {
  const int t = threadIdx.x, lane = t & 63, wave = t >> 6;
  const int wm = (wave >> 1) * (MT * 16), wn = (wave & 1) * 64;
  const int row16 = lane & 15, quad = lane >> 4;
  const int l8 = lane >> 3;
  const int cswz = (lane & 7) ^ l8;     // source k-chunk for this lane

  f32x4 acc[MT][4] = {};

  for (int k0 = 0; k0 < 1024; k0 += 64) {
    __syncthreads();
#pragma unroll
    for (int j = 0; j < MT; ++j) {
      int r = wave * (MT * 8) + j * 8 + l8;
      gload_lds16(Ap + (size_t)r * 1024 + k0 + cswz * 8,
                  &As[wave * (MT * 512) + j * 512]);
    }
#pragma unroll
    for (int j = 0; j < 4; ++j) {
      int r = wave * 32 + j * 8 + l8;
      gload_lds16(BT + (size_t)(tile_n + r) * 1024 + k0 + cswz * 8,
                  &Bs[wave * 2048 + j * 512]);
    }
    __syncthreads();

#pragma unroll
    for (int kb = 0; kb < 2; ++kb) {
      bf16x8 a_frag[MT], b_frag[4];
#pragma unroll
      for (int i = 0; i < MT; ++i)
        a_frag[i] = *(const bf16x8*)&As[swz(wm + i * 16 + row16, kb * 4 + quad)];
#pragma unroll
      for (int j = 0; j < 4; ++j)
        b_frag[j] = *(const bf16x8*)&Bs[swz(wn + j * 16 + row16, kb * 4 + quad)];
#pragma unroll
      for (int i = 0; i < MT; ++i)
#pragma unroll
        for (int j = 0; j < 4; ++j)
          acc[i][j] = __builtin_amdgcn_mfma_f32_16x16x32_bf16(
              a_frag[i], b_frag[j], acc[i][j], 0, 0, 0);
    }
  }

  // C/D layout: col = lane&15, row = quad*4 + reg
#pragma unroll
  for (int j = 0; j < 4; ++j) {
    int n = tile_n + wn + j * 16 + row16;
    float bb = bias[n];
#pragma unroll
    for (int i = 0; i < MT; ++i) {
      int m0 = wm + i * 16 + quad * 4;
      if (OMODE == 2) {
        union { u16 h[4]; u64 q; } o;
#pragma unroll
        for (int r = 0; r < 4; ++r) o.h[r] = f2bf(acc[i][j][r] + bb);
        *(u64*)((u16*)Cp + (size_t)n * 8192 + tile_m + m0) = o.q;
      } else {
#pragma unroll
        for (int r = 0; r < 4; ++r) {
          float val = acc[i][j][r] + bb;
          if (OMODE == 1) ((float*)Cp)[(size_t)(m0 + r) * 1024 + n] = val;
          else            ((u16*)Cp)[(size_t)(m0 + r) * 1024 + n] = f2bf(val);
        }
      }
    }
  }
}

// blocks 0..1023 = K/V over A=[xb;fsqb;posb]; 1024..1151 = Q over fsqb.
// XCD swizzle (xcd = bid&7): each XCD gets a contiguous tm-slab.
__global__ __launch_bounds__(256) void proj_gemm(const u16* __restrict__ xb,
                                                 const u16* __restrict__ fsqb,
                                                 const u16* __restrict__ posb,
                                                 const u16* __restrict__ WkT,
                                                 const u16* __restrict__ WvT,
                                                 const u16* __restrict__ WqT,
                                                 const float* __restrict__ bk,
                                                 const float* __restrict__ bv,
                                                 const float* __restrict__ bq,
                                                 u16* __restrict__ Kp,
                                                 u16* __restrict__ VpT,
                                                 u16* __restrict__ Qp) {
  __shared__ u16 As[128 * 64];
  __shared__ u16 Bs[128 * 64];
  int bid = blockIdx.x;
  if (bid < 1024) {
    int xcd = bid & 7, i = bid >> 3;
    int tm = xcd * 8 + (i & 7);        // 0..63
    int tn = i >> 3;                   // 0..15
    const u16* Ap;
    if (tm < 32)      Ap = xb   + (size_t)tm * 128 * 1024;
    else if (tm < 48) Ap = fsqb + (size_t)(tm - 32) * 128 * 1024;
    else              Ap = posb + (size_t)(tm - 48) * 128 * 1024;
    if (tn < 8)
      gemm_body<4, 0>(As, Bs, Ap, WkT, bk,
                      Kp + (size_t)tm * 128 * 1024, tn * 128, 0);
    else
      gemm_body<4, 2>(As, Bs, Ap, WvT, bv, VpT, (tn - 8) * 128, tm * 128);
  } else {
    int qb = bid - 1024;
    int tn = qb & 7, tm = qb >> 3;
    gemm_body<4, 0>(As, Bs, fsqb + (size_t)tm * 128 * 1024, WqT, bq,
                    Qp + (size_t)tm * 128 * 1024, tn * 128, 0);
  }
}

// BM=64: 512 blocks linear; XCD tm-slab swizzle.
__global__ __launch_bounds__(256) void out_gemm(const u16* __restrict__ Att,
                                                const u16* __restrict__ WoT,
                                                const float* __restrict__ bo,
                                                float* __restrict__ Out) {
  __shared__ u16 As[64 * 64];
  __shared__ u16 Bs[128 * 64];
  int bid = blockIdx.x;
  int xcd = bid & 7, idx = bid >> 3;
  int tm = xcd * 8 + (idx & 7);        // 0..63
  int tile_n = (idx >> 3) * 128;       // 0..7 -> n
  gemm_body<2, 1>(As, Bs, Att + (size_t)tm * 64 * 1024, WoT, bo,
                  Out + (size_t)tm * 64 * 1024, tile_n, 0);
}

// ---------------------------------------------------------------------------
// MFMA attention tile: block = (b, h, 32 s).  ~35 KB LDS, DMA staging.
// Window shifted: table col w' in [0,64) maps to global key row g = s0+w'-16
// (16-aligned base -> 16B-aligned DMA).  Valid band: w' in [s+1, s+31].
// Tables: Q/P [32]x72, KP/KF [32]x72 (reg-staged), KW [64]x64, VT [64 e]x64
// (both DMA from Kp rows / VpT rows).  Boundary blocks (s0=0,2016): reg path.
// smP[32][36]: 0..30 band scores, 31/32 diag scores, 33/34 diag probs.
// ---------------------------------------------------------------------------
#define QS   0          // 32 rows x 72 (Q, then P)
#define KPS  2304       // 32 x 72
#define KFS  4608       // 32 x 72
#define KWS  6912       // 64 x 64
#define VTS  11008      // 64 x 64
#define SMT  15104

__global__ __launch_bounds__(256) void attn_tile(const u16* __restrict__ Qp,
                                                 const u16* __restrict__ Kp,
                                                 const u16* __restrict__ VpT,
                                                 const float* __restrict__ bk,
                                                 const float* __restrict__ bv,
                                                 u16* __restrict__ Att) {
  __shared__ u16 sm[SMT];
  __shared__ float smP[32 * 36];

  const int t = threadIdx.x;
  const int bid = blockIdx.x;
  const int s0 = (bid & 63) * 32;
  const int h  = (bid >> 6) & 15;
  const int b  = bid >> 10;
  const int lane = t & 63, wave = t >> 6;
  const int row16 = lane & 15, quad = lane >> 4;
  const int hcol = h * 64;

  // ---- Q rows (register path, always valid) ----
  { int w = t >> 3, oct = t & 7;
    *(uint4*)&sm[QS + w * 72 + oct * 8] =
        *(const uint4*)(Qp + (size_t)(s0 + w) * 1024 + hcol + oct * 8); }
  // ---- KP (pos) / KF (fsq) rows (register path, always valid) ----
  { int r = t >> 3, oct = t & 7;
    *(uint4*)&sm[KPS + r * 72 + oct * 8] =
        *(const uint4*)(Kp + (size_t)(6144 + s0 + r) * 1024 + hcol + oct * 8);
    *(uint4*)&sm[KFS + r * 72 + oct * 8] =
        *(const uint4*)(Kp + (size_t)(4096 + s0 + r) * 1024 + hcol + oct * 8); }

  const bool boundary = (s0 == 0) || (s0 == 2016);
  if (!boundary) {
    // ---- DMA: KW rows w'=0..63 from Kp; VT rows e=0..63 from VpT ----
#pragma unroll
    for (int i = 0; i < 2; ++i) {
      int task = i * 256 + t;
      int w = task >> 3, oct = task & 7;
      gload_lds16(Kp + (size_t)(b * 2048 + s0 + w - 16) * 1024 + hcol + oct * 8,
                  &sm[KWS + (i * 256 + wave * 64) * 8]);
      int e = w;   // same decomposition
      gload_lds16(VpT + (size_t)(hcol + e) * 8192 + (b * 2048 + s0 - 16) + oct * 8,
                  &sm[VTS + (i * 256 + wave * 64) * 8]);
    }
  } else {
#pragma unroll
    for (int i = 0; i < 2; ++i) {
      int task = i * 256 + t;
      int w = task >> 3, oct = task & 7;
      int g = s0 + w - 16;
      uint4 kv;
      if ((unsigned)g < 2048u)
        kv = *(const uint4*)(Kp + (size_t)(b * 2048 + g) * 1024 + hcol + oct * 8);
      else
        kv = pack8(*(const float4*)(bk + hcol + oct * 8),
                   *(const float4*)(bk + hcol + oct * 8 + 4));
      *(uint4*)&sm[KWS + w * 64 + oct * 8] = kv;

      int e = w;
      int g0 = s0 + oct * 8 - 16;            // oct-granular OOB
      uint4 vv;
      if (g0 >= 0 && g0 + 7 < 2048)
        vv = *(const uint4*)(VpT + (size_t)(hcol + e) * 8192 + (b * 2048 + g0));
      else {
        u16 hb = f2bf(bv[hcol + e]);
        u32 pp = (u32)hb | ((u32)hb << 16);
        vv = make_uint4(pp, pp, pp, pp);
      }
      *(uint4*)&sm[VTS + e * 64 + oct * 8] = vv;
    }
  }
  __syncthreads();

  // ---- scores: wave handles key block [wave*16, wave*16+16) ----
  {
    f32x4 accS[2] = {};
#pragma unroll
    for (int kc = 0; kc < 2; ++kc) {
      bf16x8 bf_ = *(const bf16x8*)&sm[KWS + (wave * 16 + row16) * 64 + kc * 32 + quad * 8];
#pragma unroll
      for (int mi = 0; mi < 2; ++mi) {
        bf16x8 af = *(const bf16x8*)&sm[QS + (mi * 16 + row16) * 72 + kc * 32 + quad * 8];
        accS[mi] = __builtin_amdgcn_mfma_f32_16x16x32_bf16(af, bf_, accS[mi], 0, 0, 0);
      }
    }
#pragma unroll
    for (int mi = 0; mi < 2; ++mi)
#pragma unroll
      for (int r = 0; r < 4; ++r) {
        int s = mi * 16 + quad * 4 + r;
        int w = wave * 16 + row16;
        int d = w - s;                       // valid keys: d in [1,31]
        if (d >= 1 && d <= 31) smP[s * 36 + d - 1] = accS[mi][r] * 0.125f;
      }
  }
  if (t < 64) {                              // diag scores (pos,fsq)
    int s = t >> 1, which = t & 1;
    int base = (which == 0) ? KPS : KFS;
    float a = 0.f;
#pragma unroll
    for (int c = 0; c < 8; ++c)
      a += dot8(*(const uint4*)&sm[QS + s * 72 + c * 8],
                *(const uint4*)&sm[base + s * 72 + c * 8]);
    smP[s * 36 + 31 + which] = a * 0.125f;
  }
  __syncthreads();

  // ---- softmax (t<32); P band overwrites Q rows; diag probs stay fp32 ----
  if (t < 32) {
    int s = t;
    float vals[33];
#pragma unroll
    for (int k = 0; k < 33; ++k) vals[k] = smP[s * 36 + k];
    float mx = -1e30f;
#pragma unroll
    for (int k = 0; k < 33; ++k) mx = fmaxf(mx, vals[k]);
    float sum = 0.f;
#pragma unroll
    for (int k = 0; k < 33; ++k) { vals[k] = __expf(vals[k] - mx); sum += vals[k]; }
    float inv = 1.f / sum;
    u32* prow = (u32*)&sm[QS + s * 72];
#pragma unroll
    for (int j = 0; j < 32; ++j) prow[j] = 0;            // zero cols 0..63
#pragma unroll
    for (int k = 0; k < 31; ++k)
      sm[QS + s * 72 + (s + 1 + k)] = f2bf(vals[k] * inv); // band w' = s+1+k
    smP[s * 36 + 33] = vals[31] * inv;                   // pos
    smP[s * 36 + 34] = vals[32] * inv;                   // fsq
  }
  __syncthreads();

  // ---- PV: wave handles e block [wave*16, wave*16+16) ----
  {
    f32x4 accO[2] = {};
#pragma unroll
    for (int kc = 0; kc < 2; ++kc) {
      bf16x8 bf_ = *(const bf16x8*)&sm[VTS + (wave * 16 + row16) * 64 + kc * 32 + quad * 8];
#pragma unroll
      for (int mi = 0; mi < 2; ++mi) {
        bf16x8 af = *(const bf16x8*)&sm[QS + (mi * 16 + row16) * 72 + kc * 32 + quad * 8];
        accO[mi] = __builtin_amdgcn_mfma_f32_16x16x32_bf16(af, bf_, accO[mi], 0, 0, 0);
      }
    }
#pragma unroll
    for (int mi = 0; mi < 2; ++mi)
#pragma unroll
      for (int r = 0; r < 4; ++r) {
        int s = mi * 16 + quad * 4 + r;
        int e = wave * 16 + row16;
        float o = accO[mi][r]
                + smP[s * 36 + 33] * bf2f(VpT[(size_t)(hcol + e) * 8192 + 6144 + s0 + s])
                + smP[s * 36 + 34] * bf2f(VpT[(size_t)(hcol + e) * 8192 + 4096 + s0 + s]);
        Att[(size_t)(b * 2048 + s0 + s) * 1024 + hcol + e] = f2bf(o);
      }
  }
}

// ---------------------------------------------------------------------------
extern "C" void kernel_launch(void* const* d_in, const int* in_sizes, int n_in,
                              void* d_out, int out_size, void* d_ws, size_t ws_size,
                              hipStream_t stream) {
  (void)in_sizes; (void)n_in; (void)out_size; (void)ws_size;

  const float* x   = (const float*)d_in[0];
  const float* fsq = (const float*)d_in[1];
  const float* pos = (const float*)d_in[2];
  const float* Wq  = (const float*)d_in[3];
  const float* bq  = (const float*)d_in[4];
  const float* Wk  = (const float*)d_in[5];
  const float* bk  = (const float*)d_in[6];
  const float* Wv  = (const float*)d_in[7];
  const float* bv  = (const float*)d_in[8];
  const float* Wo  = (const float*)d_in[9];
  const float* bo  = (const float*)d_in[10];

  u16* ws = (u16*)d_ws;
  const size_t M1 = 1024 * 1024;
  u16* WqT  = ws + 0 * M1;   // 1M
  u16* WkT  = ws + 1 * M1;   // 1M
  u16* WvT  = ws + 2 * M1;   // 1M
  u16* WoT  = ws + 3 * M1;   // 1M
  u16* Qp   = ws + 4 * M1;   // 2M : 2048x1024
  u16* Kp   = ws + 6 * M1;   // 8M : 8192x1024 row-major
  u16* VpT  = ws + 14 * M1;  // 8M : 1024(n) x 8192(m) TRANSPOSED
  u16* fsqb = ws + 22 * M1;  // 2M
  u16* posb = ws + 24 * M1;  // 2M
  u16* xb   = ws + 26 * M1;  // 4M : 4096x1024
  u16* Att  = ws + 22 * M1;  // 4M, aliases fsqb+posb (dead after proj_gemm)
  // peak 30M u16 = 60 MB

  prep<<<5120, 256, 0, stream>>>(x, fsq, pos, Wq, Wk, Wv, Wo,
                                 xb, fsqb, posb, WqT, WkT, WvT, WoT);

  proj_gemm<<<1152, 256, 0, stream>>>(xb, fsqb, posb, WkT, WvT, WqT,
                                      bk, bv, bq, Kp, VpT, Qp);

  attn_tile<<<2048, 256, 0, stream>>>(Qp, Kp, VpT, bk, bv, Att);

  out_gemm<<<512, 256, 0, stream>>>(Att, WoT, bo, (float*)d_out);
}

// Round 9
// 197.079 us; speedup vs baseline: 1.0290x; 1.0290x over previous
//
#include <hip/hip_runtime.h>

// ---------------------------------------------------------------------------
// IntraModalityEnhance — fp32 in/out, bf16 MFMA internals.
// B=2, S=2048, D=1024, H=16, HD=64, E=1024, W=31 (+pos,+fsq keys = 33).
//
//  prep       : ONE launch — x/fsq/pos -> bf16  +  Wq/Wk/Wv/Wo transposes
//  proj_gemm  : ONE launch, 1152 blocks, R6 linear mapping (XCD swizzle cut
//               FETCH 87->50MB but cost +4us — proj is not BW-bound; reverted).
//               K -> Kp row-major; V x-rows -> VpT[n][4096] (transposed, for
//               attn's VT DMA); V fsq/pos rows -> Vd row-major (diag epilogue
//               reads must be coalesced — R7's VpT scatter fetched ~64KB/block
//               of junk); Q -> Qp.  Single hoisted 32KB LDS.
//  attn_tile  : block=(b,h,32 s); DMA staging, MFMA QK^T/PV, 35KB -> 4 blk/CU
//  out_gemm   : BM=64, 512 blocks, linear mapping -> d_out fp32
// ---------------------------------------------------------------------------

typedef __attribute__((ext_vector_type(8))) short bf16x8;
typedef __attribute__((ext_vector_type(4))) float f32x4;
typedef unsigned short u16;
typedef unsigned int u32;
typedef unsigned long long u64;

__device__ __forceinline__ float bf2f(u16 u) {
  union { u32 i; float f; } v; v.i = ((u32)u) << 16; return v.f;
}
__device__ __forceinline__ u16 f2bf(float f) {
  union { float f; u32 i; } v; v.f = f;
  u32 r = v.i + 0x7fffu + ((v.i >> 16) & 1u);
  return (u16)(r >> 16);
}
__device__ __forceinline__ float2 unpk(u32 u) {
  union { u32 i; float f; } lo, hi;
  lo.i = u << 16; hi.i = u & 0xffff0000u;
  return make_float2(lo.f, hi.f);
}
__device__ __forceinline__ float dot8(uint4 a, uint4 b) {
  float s = 0.f;
  { float2 x = unpk(a.x), y = unpk(b.x); s += x.x*y.x + x.y*y.y; }
  { float2 x = unpk(a.y), y = unpk(b.y); s += x.x*y.x + x.y*y.y; }
  { float2 x = unpk(a.z), y = unpk(b.z); s += x.x*y.x + x.y*y.y; }
  { float2 x = unpk(a.w), y = unpk(b.w); s += x.x*y.x + x.y*y.y; }
  return s;
}
__device__ __forceinline__ void gload_lds16(const u16* g, u16* l) {
  __builtin_amdgcn_global_load_lds((const __attribute__((address_space(1))) void*)(g),
                                   (__attribute__((address_space(3))) void*)(l),
                                   16, 0, 0);
}
__device__ __forceinline__ uint4 pack8(float4 a, float4 b) {
  union { u16 h[8]; uint4 q; } u;
  u.h[0] = f2bf(a.x); u.h[1] = f2bf(a.y); u.h[2] = f2bf(a.z); u.h[3] = f2bf(a.w);
  u.h[4] = f2bf(b.x); u.h[5] = f2bf(b.y); u.h[6] = f2bf(b.z); u.h[7] = f2bf(b.w);
  return u.q;
}

// ---------------------------------------------------------------------------
__device__ __forceinline__ void transpose_body(const float* src, u16* dst,
                                               int R, int C, int r0, int c0) {
  __shared__ u16 tile[64][72];
  int t = threadIdx.x;
#pragma unroll
  for (int i = 0; i < 16; ++i) {
    int idx = i * 256 + t;
    int r = idx >> 6, c = idx & 63;
    tile[r][c] = f2bf(src[(size_t)(r0 + r) * C + (c0 + c)]);
  }
  __syncthreads();
#pragma unroll
  for (int i = 0; i < 16; ++i) {
    int idx = i * 256 + t;
    int c = idx >> 6, r = idx & 63;
    dst[(size_t)(c0 + c) * R + (r0 + r)] = tile[r][c];
  }
}

// ONE launch: blocks 0..4095 convert x/fsq/pos; 4096..5119 transpose weights.
__global__ __launch_bounds__(256) void prep(const float* __restrict__ x,
                                            const float* __restrict__ fsq,
                                            const float* __restrict__ pos,
                                            const float* __restrict__ Wq,
                                            const float* __restrict__ Wk,
                                            const float* __restrict__ Wv,
                                            const float* __restrict__ Wo,
                                            u16* __restrict__ xb,
                                            u16* __restrict__ fsqb,
                                            u16* __restrict__ posb,
                                            u16* __restrict__ WqT,
                                            u16* __restrict__ WkT,
                                            u16* __restrict__ WvT,
                                            u16* __restrict__ WoT) {
  int bid = blockIdx.x;
  if (bid < 4096) {
    int i = bid * 256 + threadIdx.x;
    const float* src; u16* dst; int off;
    if (i < 524288)      { src = x;   dst = xb;   off = i; }
    else if (i < 786432) { src = fsq; dst = fsqb; off = i - 524288; }
    else                 { src = pos; dst = posb; off = i - 786432; }
    float4 a = ((const float4*)src)[2 * off];
    float4 b = ((const float4*)src)[2 * off + 1];
    ((uint4*)dst)[off] = pack8(a, b);
  } else {
    int id = bid - 4096;
    int z = id >> 8, rest = id & 255;
    int xx = rest & 15, yy = rest >> 4;
    if (z < 3) {
      const float* s = (z == 0) ? Wq : (z == 1) ? Wk : Wv;
      u16* d = (z == 0) ? WqT : (z == 1) ? WkT : WvT;
      size_t off = (size_t)xx * 65536;    // head * 1024 * 64
      transpose_body(s + off, d + off, 1024, 64, yy * 64, 0);
    } else {
      transpose_body(Wo, WoT, 1024, 1024, yy * 64, xx * 64);
    }
  }
}

// ---------------------------------------------------------------------------
// GEMM body: BM = MT*32, BN=128, BK=64, XOR-swizzled LDS, global_load_lds x16.
// LDS buffers caller-owned (one allocation shared by all inlined variants).
// OMODE: 0 = bf16 row-major C[m][1024], 1 = fp32 row-major,
//        2 = bf16 TRANSPOSED CT[n][4096] (packed 4-elem 8B stores).
// ---------------------------------------------------------------------------
__device__ __forceinline__ int swz(int R, int c) {   // u16 index of 16B chunk
  return (R * 8 + (c ^ (R & 7))) * 8;
}

template <int MT, int OMODE>
__device__ __forceinline__ void gemm_body(u16* __restrict__ As,
                                          u16* __restrict__ Bs,
                                          const u16* __restrict__ Ap,
                                          const u16* __restrict__ BT,
                                          const float* __restrict__ bias,
                                          void* Cp, int tile_n, int tile_m) {
  const int t = threadIdx.x, lane = t & 63, wave = t >> 6;
  const int wm = (wave >> 1) * (MT * 16), wn = (wave & 1) * 64;
  const int row16 = lane & 15, quad = lane >> 4;
  const int l8 = lane >> 3;
  const int cswz = (lane & 7) ^ l8;     // source k-chunk for this lane

  f32x4 acc[MT][4] = {};

  for (int k0 = 0; k0 < 1024; k0 += 64) {
    __syncthreads();
#pragma unroll
    for (int j = 0; j < MT; ++j) {
      int r = wave * (MT * 8) + j * 8 + l8;
      gload_lds16(Ap + (size_t)r * 1024 + k0 + cswz * 8,
                  &As[wave * (MT * 512) + j * 512]);
    }
#pragma unroll
    for (int j = 0; j < 4; ++j) {
      int r = wave * 32 + j * 8 + l8;
      gload_lds16(BT + (size_t)(tile_n + r) * 1024 + k0 + cswz * 8,
                  &Bs[wave * 2048 + j * 512]);
    }
    __syncthreads();

#pragma unroll
    for (int kb = 0; kb < 2; ++kb) {
      bf16x8 a_frag[MT], b_frag[4];
#pragma unroll
      for (int i = 0; i < MT; ++i)
        a_frag[i] = *(const bf16x8*)&As[swz(wm + i * 16 + row16, kb * 4 + quad)];
#pragma unroll
      for (int j = 0; j < 4; ++j)
        b_frag[j] = *(const bf16x8*)&Bs[swz(wn + j * 16 + row16, kb * 4 + quad)];
#pragma unroll
      for (int i = 0; i < MT; ++i)
#pragma unroll
        for (int j = 0; j < 4; ++j)
          acc[i][j] = __builtin_amdgcn_mfma_f32_16x16x32_bf16(
              a_frag[i], b_frag[j], acc[i][j], 0, 0, 0);
    }
  }

  // C/D layout: col = lane&15, row = quad*4 + reg
#pragma unroll
  for (int j = 0; j < 4; ++j) {
    int n = tile_n + wn + j * 16 + row16;
    float bb = bias[n];
#pragma unroll
    for (int i = 0; i < MT; ++i) {
      int m0 = wm + i * 16 + quad * 4;
      if (OMODE == 2) {
        union { u16 h[4]; u64 q; } o;
#pragma unroll
        for (int r = 0; r < 4; ++r) o.h[r] = f2bf(acc[i][j][r] + bb);
        *(u64*)((u16*)Cp + (size_t)n * 4096 + tile_m + m0) = o.q;
      } else {
#pragma unroll
        for (int r = 0; r < 4; ++r) {
          float val = acc[i][j][r] + bb;
          if (OMODE == 1) ((float*)Cp)[(size_t)(m0 + r) * 1024 + n] = val;
          else            ((u16*)Cp)[(size_t)(m0 + r) * 1024 + n] = f2bf(val);
        }
      }
    }
  }
}

// blocks 0..1023 = K/V over A=[xb;fsqb;posb]; 1024..1151 = Q over fsqb.
// Linear mapping (R6).  V: x-rows (tm<32) -> VpT transposed; fsq/pos rows
// (tm>=32) -> Vd row-major (attn reads them diagonally — must be coalesced).
__global__ __launch_bounds__(256) void proj_gemm(const u16* __restrict__ xb,
                                                 const u16* __restrict__ fsqb,
                                                 const u16* __restrict__ posb,
                                                 const u16* __restrict__ WkT,
                                                 const u16* __restrict__ WvT,
                                                 const u16* __restrict__ WqT,
                                                 const float* __restrict__ bk,
                                                 const float* __restrict__ bv,
                                                 const float* __restrict__ bq,
                                                 u16* __restrict__ Kp,
                                                 u16* __restrict__ VpT,
                                                 u16* __restrict__ Vd,
                                                 u16* __restrict__ Qp) {
  __shared__ u16 As[128 * 64];
  __shared__ u16 Bs[128 * 64];
  int bid = blockIdx.x;
  if (bid < 1024) {
    int tm = bid >> 4, tn = bid & 15;
    const u16* Ap;
    if (tm < 32)      Ap = xb   + (size_t)tm * 128 * 1024;
    else if (tm < 48) Ap = fsqb + (size_t)(tm - 32) * 128 * 1024;
    else              Ap = posb + (size_t)(tm - 48) * 128 * 1024;
    if (tn < 8) {
      gemm_body<4, 0>(As, Bs, Ap, WkT, bk,
                      Kp + (size_t)tm * 128 * 1024, tn * 128, 0);
    } else if (tm < 32) {
      gemm_body<4, 2>(As, Bs, Ap, WvT, bv, VpT, (tn - 8) * 128, tm * 128);
    } else {
      gemm_body<4, 0>(As, Bs, Ap, WvT, bv,
                      Vd + (size_t)(tm - 32) * 128 * 1024, (tn - 8) * 128, 0);
    }
  } else {
    int qb = bid - 1024;
    int tm = qb >> 3, tn = qb & 7;
    gemm_body<4, 0>(As, Bs, fsqb + (size_t)tm * 128 * 1024, WqT, bq,
                    Qp + (size_t)tm * 128 * 1024, tn * 128, 0);
  }
}

// BM=64: grid (8, 64), linear mapping.
__global__ __launch_bounds__(256) void out_gemm(const u16* __restrict__ Att,
                                                const u16* __restrict__ WoT,
                                                const float* __restrict__ bo,
                                                float* __restrict__ Out) {
  __shared__ u16 As[64 * 64];
  __shared__ u16 Bs[128 * 64];
  int tile_n = blockIdx.x * 128, tm = blockIdx.y;
  gemm_body<2, 1>(As, Bs, Att + (size_t)tm * 64 * 1024, WoT, bo,
                  Out + (size_t)tm * 64 * 1024, tile_n, 0);
}

// ---------------------------------------------------------------------------
// MFMA attention tile: block = (b, h, 32 s).  ~35 KB LDS -> 4 blocks/CU.
// Window shifted: table col w' in [0,64) maps to global key row g = s0+w'-16.
// Valid band: w' in [s+1, s+31].
// Tables: Q/P [32]x72, KP/KF [32]x72 (reg-staged), KW [64]x64 (DMA from Kp),
// VT [64 e]x64 (DMA from VpT x-half).  Boundary blocks (s0=0,2016): reg path.
// Diag-V (pos/fsq) read from row-major Vd in the epilogue (coalesced).
// smP[32][36]: 0..30 band scores, 31/32 diag scores, 33/34 diag probs.
// ---------------------------------------------------------------------------
#define QS   0          // 32 rows x 72 (Q, then P)
#define KPS  2304       // 32 x 72
#define KFS  4608       // 32 x 72
#define KWS  6912       // 64 x 64
#define VTS  11008      // 64 x 64
#define SMT  15104

__global__ __launch_bounds__(256) void attn_tile(const u16* __restrict__ Qp,
                                                 const u16* __restrict__ Kp,
                                                 const u16* __restrict__ VpT,
                                                 const u16* __restrict__ Vd,
                                                 const float* __restrict__ bk,
                                                 const float* __restrict__ bv,
                                                 u16* __restrict__ Att) {
  __shared__ u16 sm[SMT];
  __shared__ float smP[32 * 36];

  const int t = threadIdx.x;
  const int bid = blockIdx.x;
  const int s0 = (bid & 63) * 32;
  const int h  = (bid >> 6) & 15;
  const int b  = bid >> 10;
  const int lane = t & 63, wave = t >> 6;
  const int row16 = lane & 15, quad = lane >> 4;
  const int hcol = h * 64;

  // ---- Q rows (register path, always valid) ----
  { int w = t >> 3, oct = t & 7;
    *(uint4*)&sm[QS + w * 72 + oct * 8] =
        *(const uint4*)(Qp + (size_t)(s0 + w) * 1024 + hcol + oct * 8); }
  // ---- KP (pos) / KF (fsq) rows (register path, always valid) ----
  { int r = t >> 3, oct = t & 7;
    *(uint4*)&sm[KPS + r * 72 + oct * 8] =
        *(const uint4*)(Kp + (size_t)(6144 + s0 + r) * 1024 + hcol + oct * 8);
    *(uint4*)&sm[KFS + r * 72 + oct * 8] =
        *(const uint4*)(Kp + (size_t)(4096 + s0 + r) * 1024 + hcol + oct * 8); }

  const bool boundary = (s0 == 0) || (s0 == 2016);
  if (!boundary) {
    // ---- DMA: KW rows w'=0..63 from Kp; VT rows e=0..63 from VpT ----
#pragma unroll
    for (int i = 0; i < 2; ++i) {
      int task = i * 256 + t;
      int w = task >> 3, oct = task & 7;
      gload_lds16(Kp + (size_t)(b * 2048 + s0 + w - 16) * 1024 + hcol + oct * 8,
                  &sm[KWS + (i * 256 + wave * 64) * 8]);
      int e = w;   // same decomposition
      gload_lds16(VpT + (size_t)(hcol + e) * 4096 + (b * 2048 + s0 - 16) + oct * 8,
                  &sm[VTS + (i * 256 + wave * 64) * 8]);
    }
  } else {
#pragma unroll
    for (int i = 0; i < 2; ++i) {
      int task = i * 256 + t;
      int w = task >> 3, oct = task & 7;
      int g = s0 + w - 16;
      uint4 kv;
      if ((unsigned)g < 2048u)
        kv = *(const uint4*)(Kp + (size_t)(b * 2048 + g) * 1024 + hcol + oct * 8);
      else
        kv = pack8(*(const float4*)(bk + hcol + oct * 8),
                   *(const float4*)(bk + hcol + oct * 8 + 4));
      *(uint4*)&sm[KWS + w * 64 + oct * 8] = kv;

      int e = w;
      int g0 = s0 + oct * 8 - 16;            // oct-granular OOB
      uint4 vv;
      if (g0 >= 0 && g0 + 7 < 2048)
        vv = *(const uint4*)(VpT + (size_t)(hcol + e) * 4096 + (b * 2048 + g0));
      else {
        u16 hb = f2bf(bv[hcol + e]);
        u32 pp = (u32)hb | ((u32)hb << 16);
        vv = make_uint4(pp, pp, pp, pp);
      }
      *(uint4*)&sm[VTS + e * 64 + oct * 8] = vv;
    }
  }
  __syncthreads();

  // ---- scores: wave handles key block [wave*16, wave*16+16) ----
  {
    f32x4 accS[2] = {};
#pragma unroll
    for (int kc = 0; kc < 2; ++kc) {
      bf16x8 bf_ = *(const bf16x8*)&sm[KWS + (wave * 16 + row16) * 64 + kc * 32 + quad * 8];
#pragma unroll
      for (int mi = 0; mi < 2; ++mi) {
        bf16x8 af = *(const bf16x8*)&sm[QS + (mi * 16 + row16) * 72 + kc * 32 + quad * 8];
        accS[mi] = __builtin_amdgcn_mfma_f32_16x16x32_bf16(af, bf_, accS[mi], 0, 0, 0);
      }
    }
#pragma unroll
    for (int mi = 0; mi < 2; ++mi)
#pragma unroll
      for (int r = 0; r < 4; ++r) {
        int s = mi * 16 + quad * 4 + r;
        int w = wave * 16 + row16;
        int d = w - s;                       // valid keys: d in [1,31]
        if (d >= 1 && d <= 31) smP[s * 36 + d - 1] = accS[mi][r] * 0.125f;
      }
  }
  if (t < 64) {                              // diag scores (pos,fsq)
    int s = t >> 1, which = t & 1;
    int base = (which == 0) ? KPS : KFS;
    float a = 0.f;
#pragma unroll
    for (int c = 0; c < 8; ++c)
      a += dot8(*(const uint4*)&sm[QS + s * 72 + c * 8],
                *(const uint4*)&sm[base + s * 72 + c * 8]);
    smP[s * 36 + 31 + which] = a * 0.125f;
  }
  __syncthreads();

  // ---- softmax (t<32); P band overwrites Q rows; diag probs stay fp32 ----
  if (t < 32) {
    int s = t;
    float vals[33];
#pragma unroll
    for (int k = 0; k < 33; ++k) vals[k] = smP[s * 36 + k];
    float mx = -1e30f;
#pragma unroll
    for (int k = 0; k < 33; ++k) mx = fmaxf(mx, vals[k]);
    float sum = 0.f;
#pragma unroll
    for (int k = 0; k < 33; ++k) { vals[k] = __expf(vals[k] - mx); sum += vals[k]; }
    float inv = 1.f / sum;
    u32* prow = (u32*)&sm[QS + s * 72];
#pragma unroll
    for (int j = 0; j < 32; ++j) prow[j] = 0;            // zero cols 0..63
#pragma unroll
    for (int k = 0; k < 31; ++k)
      sm[QS + s * 72 + (s + 1 + k)] = f2bf(vals[k] * inv); // band w' = s+1+k
    smP[s * 36 + 33] = vals[31] * inv;                   // pos
    smP[s * 36 + 34] = vals[32] * inv;                   // fsq
  }
  __syncthreads();

  // ---- PV: wave handles e block [wave*16, wave*16+16) ----
  {
    f32x4 accO[2] = {};
#pragma unroll
    for (int kc = 0; kc < 2; ++kc) {
      bf16x8 bf_ = *(const bf16x8*)&sm[VTS + (wave * 16 + row16) * 64 + kc * 32 + quad * 8];
#pragma unroll
      for (int mi = 0; mi < 2; ++mi) {
        bf16x8 af = *(const bf16x8*)&sm[QS + (mi * 16 + row16) * 72 + kc * 32 + quad * 8];
        accO[mi] = __builtin_amdgcn_mfma_f32_16x16x32_bf16(af, bf_, accO[mi], 0, 0, 0);
      }
    }
#pragma unroll
    for (int mi = 0; mi < 2; ++mi)
#pragma unroll
      for (int r = 0; r < 4; ++r) {
        int s = mi * 16 + quad * 4 + r;
        int e = wave * 16 + row16;
        // Vd: rows 0..2047 = fsq-V, rows 2048..4095 = pos-V (row-major,
        // e is the fast index -> coalesced 32B segments)
        float o = accO[mi][r]
                + smP[s * 36 + 33] * bf2f(Vd[(size_t)(2048 + s0 + s) * 1024 + hcol + e])
                + smP[s * 36 + 34] * bf2f(Vd[(size_t)(s0 + s) * 1024 + hcol + e]);
        Att[(size_t)(b * 2048 + s0 + s) * 1024 + hcol + e] = f2bf(o);
      }
  }
}

// ---------------------------------------------------------------------------
extern "C" void kernel_launch(void* const* d_in, const int* in_sizes, int n_in,
                              void* d_out, int out_size, void* d_ws, size_t ws_size,
                              hipStream_t stream) {
  (void)in_sizes; (void)n_in; (void)out_size; (void)ws_size;

  const float* x   = (const float*)d_in[0];
  const float* fsq = (const float*)d_in[1];
  const float* pos = (const float*)d_in[2];
  const float* Wq  = (const float*)d_in[3];
  const float* bq  = (const float*)d_in[4];
  const float* Wk  = (const float*)d_in[5];
  const float* bk  = (const float*)d_in[6];
  const float* Wv  = (const float*)d_in[7];
  const float* bv  = (const float*)d_in[8];
  const float* Wo  = (const float*)d_in[9];
  const float* bo  = (const float*)d_in[10];

  u16* ws = (u16*)d_ws;
  const size_t M1 = 1024 * 1024;
  u16* WqT  = ws + 0 * M1;   // 1M
  u16* WkT  = ws + 1 * M1;   // 1M
  u16* WvT  = ws + 2 * M1;   // 1M
  u16* WoT  = ws + 3 * M1;   // 1M
  u16* Qp   = ws + 4 * M1;   // 2M : 2048x1024
  u16* Kp   = ws + 6 * M1;   // 8M : 8192x1024 row-major
  u16* VpT  = ws + 14 * M1;  // 4M : 1024(n) x 4096(m, x-rows) TRANSPOSED
  u16* Vd   = ws + 18 * M1;  // 4M : 4096x1024 row-major (fsq-V; pos-V)
  u16* fsqb = ws + 22 * M1;  // 2M
  u16* posb = ws + 24 * M1;  // 2M
  u16* xb   = ws + 26 * M1;  // 4M : 4096x1024
  u16* Att  = ws + 22 * M1;  // 4M, aliases fsqb+posb (dead after proj_gemm)
  // peak 30M u16 = 60 MB

  prep<<<5120, 256, 0, stream>>>(x, fsq, pos, Wq, Wk, Wv, Wo,
                                 xb, fsqb, posb, WqT, WkT, WvT, WoT);

  proj_gemm<<<1152, 256, 0, stream>>>(xb, fsqb, posb, WkT, WvT, WqT,
                                      bk, bv, bq, Kp, VpT, Vd, Qp);

  attn_tile<<<2048, 256, 0, stream>>>(Qp, Kp, VpT, Vd, bk, bv, Att);

  out_gemm<<<dim3(8, 64), 256, 0, stream>>>(Att, WoT, bo, (float*)d_out);
}